// Round 5
// baseline (2296.909 us; speedup 1.0000x reference)
//
#include <hip/hip_runtime.h>
#include <math.h>

typedef unsigned short u16;
typedef unsigned int   u32;

#define LVLS 24
#define CAPN (1 << 18)
#define BT   128   // act LDS = 20*128*16 = 40960 B -> 4 blocks/CU cap

__device__ __forceinline__ float gelu_f(float x) {
    return 0.5f * x * (1.0f + erff(x * 0.70710678118654752f));
}

// acc[j] = b[j] + sum_k act[k] * W[k*N + j], k ascending (matches np order)
template <int K4, int N>
__device__ __forceinline__ void matvec(const float* __restrict__ Wp,
                                       const float* __restrict__ bp,
                                       const float4 (*act)[BT], int tid,
                                       float* acc) {
    #pragma unroll
    for (int j = 0; j < N; j++) acc[j] = bp[j];
    #pragma unroll 2
    for (int k4 = 0; k4 < K4; k4++) {
        float4 x = act[k4][tid];
        const float* w0 = Wp + (4 * k4 + 0) * N;
        const float* w1 = Wp + (4 * k4 + 1) * N;
        const float* w2 = Wp + (4 * k4 + 2) * N;
        const float* w3 = Wp + (4 * k4 + 3) * N;
        #pragma unroll
        for (int j = 0; j < N; j++) {
            float a = acc[j];
            a = fmaf(x.x, w0[j], a);
            a = fmaf(x.y, w1[j], a);
            a = fmaf(x.z, w2[j], a);
            a = fmaf(x.w, w3[j], a);
            acc[j] = a;
        }
    }
}

__global__ void __launch_bounds__(BT, 2) nerf_fused(
    const float* __restrict__ pos, const float* __restrict__ dirs,
    const int* __restrict__ iter,
    const float* __restrict__ tables, const int* __restrict__ shifts,
    const float* __restrict__ W1, const float* __restrict__ b1,
    const float* __restrict__ W2, const float* __restrict__ b2,
    const float* __restrict__ W3, const float* __restrict__ b3,
    const float* __restrict__ W4, const float* __restrict__ b4,
    const float* __restrict__ R1, const float* __restrict__ rb1,
    const float* __restrict__ R2, const float* __restrict__ rb2,
    const float* __restrict__ R3, const float* __restrict__ rb3,
    float* __restrict__ out, int n) {
    __shared__ float4 act[20][BT];
    int tid = threadIdx.x;
    int i = blockIdx.x * BT + tid;
    if (i >= n) return;

    float px = pos[3 * i + 0], py = pos[3 * i + 1], pz = pos[3 * i + 2];

    // window t (iter = 10000 -> all-ones window)
    double itd = (double)iter[0] / 10000.0;
    itd = itd < 0.0 ? 0.0 : (itd > 1.0 ? 1.0 : itd);
    float tL = (float)((0.3 + 0.7 * itd) * 24.0);

    // ---- hash encode fused with layer 1 ----
    float acc1[64];
    #pragma unroll
    for (int j = 0; j < 64; j++) acc1[j] = b1[j];

    #pragma unroll 2
    for (int l = 0; l < LVLS; l++) {
        float sc = powf(10.0f, (float)l * (-4.0f / 23.0f));  // ulp-diffs vs np harmless: |feat|<=1e-4
        float arg = fminf(fmaxf(tL - (float)l, 0.0f), 1.0f);
        float wl = 0.5f - 0.5f * cosf(3.14159265358979323846f * arg);
        int sx = shifts[3 * l + 0], sy = shifts[3 * l + 1], sz = shifts[3 * l + 2];
        float cx = px / sc, cy = py / sc, cz = pz / sc;
        float fx = floorf(cx), fy = floorf(cy), fz = floorf(cz);
        float rx = cx - fx, ry = cy - fy, rz = cz - fz;
        int bx = (int)fx + sx, by = (int)fy + sy, bz = (int)fz + sz;
        u32 hx0 = (u32)bx;
        u32 hx1 = (u32)(bx + 1);
        u32 hy0 = (u32)by * 2654435761u;
        u32 hy1 = (u32)(by + 1) * 2654435761u;
        u32 hz0 = (u32)bz * 805459861u;
        u32 hz1 = (u32)(bz + 1) * 805459861u;
        const float* tl = tables + 2 * ((size_t)l * CAPN);
        float a0 = 0.0f, a1 = 0.0f;
        #pragma unroll
        for (int c = 0; c < 8; c++) {
            u32 hx = (c & 1) ? hx1 : hx0;
            u32 hy = (c & 2) ? hy1 : hy0;
            u32 hz = (c & 4) ? hz1 : hz0;
            u32 idx = (hx ^ hy ^ hz) & (CAPN - 1);
            float w = ((c & 1) ? rx : 1.0f - rx);
            w *= ((c & 2) ? ry : 1.0f - ry);
            w *= ((c & 4) ? rz : 1.0f - rz);
            const float* tf = tl + 2 * (size_t)idx;
            a0 = fmaf(w, tf[0], a0);
            a1 = fmaf(w, tf[1], a1);
        }
        a0 *= wl; a1 *= wl;
        const float* w0 = W1 + (2 * l) * 64;
        #pragma unroll
        for (int j = 0; j < 64; j++) acc1[j] = fmaf(a0, w0[j], acc1[j]);
        const float* w1 = w0 + 64;
        #pragma unroll
        for (int j = 0; j < 64; j++) acc1[j] = fmaf(a1, w1[j], acc1[j]);
    }
    {   // pos rows k = 48,49,50
        const float* wr = W1 + 48 * 64;
        #pragma unroll
        for (int j = 0; j < 64; j++) acc1[j] = fmaf(px, wr[j], acc1[j]);
        wr += 64;
        #pragma unroll
        for (int j = 0; j < 64; j++) acc1[j] = fmaf(py, wr[j], acc1[j]);
        wr += 64;
        #pragma unroll
        for (int j = 0; j < 64; j++) acc1[j] = fmaf(pz, wr[j], acc1[j]);
    }
    #pragma unroll
    for (int j = 0; j < 16; j++)
        act[j][tid] = make_float4(gelu_f(acc1[4 * j + 0]), gelu_f(acc1[4 * j + 1]),
                                  gelu_f(acc1[4 * j + 2]), gelu_f(acc1[4 * j + 3]));

    // ---- layers 2,3 ----
    {
        float t2[64];
        matvec<16, 64>(W2, b2, act, tid, t2);
        #pragma unroll
        for (int j = 0; j < 16; j++)
            act[j][tid] = make_float4(gelu_f(t2[4 * j + 0]), gelu_f(t2[4 * j + 1]),
                                      gelu_f(t2[4 * j + 2]), gelu_f(t2[4 * j + 3]));
    }
    {
        float t3[64];
        matvec<16, 64>(W3, b3, act, tid, t3);
        #pragma unroll
        for (int j = 0; j < 16; j++)
            act[j][tid] = make_float4(gelu_f(t3[4 * j + 0]), gelu_f(t3[4 * j + 1]),
                                      gelu_f(t3[4 * j + 2]), gelu_f(t3[4 * j + 3]));
    }
    // ---- layer 4: density + feat_rgb ----
    {
        float fd[65];
        matvec<16, 65>(W4, b4, act, tid, fd);
        float x0 = fd[0];
        float dens = fmaxf(x0, 0.0f) + log1pf(expf(-fabsf(x0)));   // stable softplus
        out[(size_t)3 * n + i] = dens;
        #pragma unroll
        for (int j = 0; j < 16; j++)
            act[j][tid] = make_float4(gelu_f(fd[4 * j + 1]), gelu_f(fd[4 * j + 2]),
                                      gelu_f(fd[4 * j + 3]), gelu_f(fd[4 * j + 4]));
    }
    // ---- SH basis -> act rows 16..19 ----
    {
        float dx = dirs[3 * i + 0], dy = dirs[3 * i + 1], dz = dirs[3 * i + 2];
        float xx = dx * dx, yy = dy * dy, zz = dz * dz;
        float sh[16];
        sh[0]  = 0.28209479177387814f;
        sh[1]  = -0.48860251190291987f * dy;
        sh[2]  = 0.48860251190291987f * dz;
        sh[3]  = -0.48860251190291987f * dx;
        sh[4]  = 1.0925484305920792f * dx * dy;
        sh[5]  = -1.0925484305920792f * dy * dz;
        sh[6]  = 0.94617469575756f * zz - 0.31539156525252f;
        sh[7]  = -1.0925484305920792f * dx * dz;
        sh[8]  = 0.5462742152960396f * (xx - yy);
        sh[9]  = -0.5900435899266435f * dy * (3.0f * xx - yy);
        sh[10] = 2.890611442640554f * dx * dy * dz;
        sh[11] = -0.4570457994644657f * dy * (4.0f * zz - xx - yy);
        sh[12] = 0.37317633259011546f * dz * (2.0f * zz - 3.0f * xx - 3.0f * yy);
        sh[13] = -0.4570457994644657f * dx * (4.0f * zz - xx - yy);
        sh[14] = 1.445305721320277f * dz * (xx - yy);
        sh[15] = -0.5900435899266435f * dx * (xx - 3.0f * yy);
        #pragma unroll
        for (int j = 0; j < 4; j++)
            act[16 + j][tid] = make_float4(sh[4 * j + 0], sh[4 * j + 1],
                                           sh[4 * j + 2], sh[4 * j + 3]);
    }
    // ---- R1, R2, R3 ----
    {
        float h1[64];
        matvec<20, 64>(R1, rb1, act, tid, h1);
        #pragma unroll
        for (int j = 0; j < 16; j++)
            act[j][tid] = make_float4(gelu_f(h1[4 * j + 0]), gelu_f(h1[4 * j + 1]),
                                      gelu_f(h1[4 * j + 2]), gelu_f(h1[4 * j + 3]));
    }
    {
        float h2[64];
        matvec<16, 64>(R2, rb2, act, tid, h2);
        #pragma unroll
        for (int j = 0; j < 16; j++)
            act[j][tid] = make_float4(gelu_f(h2[4 * j + 0]), gelu_f(h2[4 * j + 1]),
                                      gelu_f(h2[4 * j + 2]), gelu_f(h2[4 * j + 3]));
    }
    {
        float rgb[3];
        matvec<16, 3>(R3, rb3, act, tid, rgb);
        #pragma unroll
        for (int c = 0; c < 3; c++) {
            float s = 1.0f / (1.0f + expf(-rgb[c]));
            out[(size_t)3 * i + c] = s;
        }
    }
}

extern "C" void kernel_launch(void* const* d_in, const int* in_sizes, int n_in,
                              void* d_out, int out_size, void* d_ws, size_t ws_size,
                              hipStream_t stream) {
    int n = in_sizes[0] / 3;
    int grid = (n + BT - 1) / BT;
    nerf_fused<<<grid, BT, 0, stream>>>(
        (const float*)d_in[0], (const float*)d_in[1], (const int*)d_in[2],
        (const float*)d_in[3], (const int*)d_in[4],
        (const float*)d_in[5],  (const float*)d_in[6],
        (const float*)d_in[7],  (const float*)d_in[8],
        (const float*)d_in[9],  (const float*)d_in[10],
        (const float*)d_in[11], (const float*)d_in[12],
        (const float*)d_in[13], (const float*)d_in[14],
        (const float*)d_in[15], (const float*)d_in[16],
        (const float*)d_in[17], (const float*)d_in[18],
        (float*)d_out, n);
}

// Round 7
// 1720.236 us; speedup vs baseline: 1.3352x; 1.3352x over previous
//
#include <hip/hip_runtime.h>
#include <math.h>

typedef unsigned short u16;
typedef unsigned int   u32;

#define LVLS 24
#define CAPN (1 << 18)
#define STR  81           // LDS act row stride in u32 (odd => benign bank pattern)

typedef float    f32x4 __attribute__((ext_vector_type(4)));
typedef _Float16 f16x8 __attribute__((ext_vector_type(8)));
typedef u32      u32x4 __attribute__((ext_vector_type(4)));

#if __has_builtin(__builtin_amdgcn_rcpf)
#define RCPF(x) __builtin_amdgcn_rcpf(x)
#else
#define RCPF(x) (1.0f / (x))
#endif
#if __has_builtin(__builtin_amdgcn_exp2f)
#define EXP2F(x) __builtin_amdgcn_exp2f(x)
#else
#define EXP2F(x) exp2f(x)
#endif

// ---- weight blobs in d_ws (u32 units). Per layer: 4*NKT frags, each 64 lanes x 4 u32,
// hi half then lo half: size = NKT*4*64*8 u32.
#define WB1   0
#define WB2   4096
#define WB3   8192
#define WB4   12288   /* W4 cols 1..64 */
#define WBR1  16384   /* NKT=3 */
#define WBR2  22528
#define WSTOT 26624   /* 104 KB */

__device__ __forceinline__ float h2f(u16 b) {
    union { u16 u; _Float16 h; } v; v.u = b; return (float)v.h;
}
__device__ __forceinline__ u16 f2h(float x) {
    union { _Float16 h; u16 u; } v; v.h = (_Float16)x; return v.u;   // RNE v_cvt_f16_f32
}
// fp16 hi/lo split: x = hi + lo + eps, |eps| ~ 2^-24 |x|
__device__ __forceinline__ void hsplit(float x, u16& h, u16& l) {
    h = f2h(x);
    float r = x - h2f(h);
    l = f2h(r);
}
__device__ __forceinline__ u32 packhl(float x) {
    u16 h, l; hsplit(x, h, l);
    return ((u32)h << 16) | l;
}
__device__ __forceinline__ float unpackhl(u32 w) {
    return h2f((u16)(w >> 16)) + h2f((u16)(w & 0xffffu));
}
// A&S 7.1.26 erf (|eps|<=1.5e-7), hw rcp + exp2
__device__ __forceinline__ float gelu_f(float x) {
    float z  = fabsf(x) * 0.70710678118654752f;
    float t  = RCPF(fmaf(0.3275911f, z, 1.0f));
    float e  = EXP2F(-z * z * 1.44269504088896340f);
    float p  = fmaf(1.061405429f, t, -1.453152027f);
    p = fmaf(p, t, 1.421413741f);
    p = fmaf(p, t, -0.284496736f);
    p = fmaf(p, t, 0.254829592f);
    p = p * t;
    float erfv = fmaf(-p, e, 1.0f);           // erf(|x|/sqrt2)
    float se   = copysignf(erfv, x);
    return x * fmaf(0.5f, se, 0.5f);
}
__device__ __forceinline__ float sigmoid_f(float y) {
    return RCPF(1.0f + EXP2F(-y * 1.44269504088896340f));
}
__device__ __forceinline__ f16x8 cast8h(u32 a, u32 b, u32 c, u32 d) {
    union { u32 u[4]; f16x8 h; } v; v.u[0]=a; v.u[1]=b; v.u[2]=c; v.u[3]=d; return v.h;
}

// ================= prep: split weights into frag-ordered hi/lo fp16 blobs =================
struct PrepA { const float* W[6]; u32* ws; };

__global__ void prep_weights(PrepA a) {
    int tid = blockIdx.x * 256 + threadIdx.x;   // one per (frag,j) pair -> writes hi & lo u32
    if (tid >= 13312) return;
    int p = tid, base, nkt, Ksrc, ldm, coloff, layer;
    if      (p < 2048)  { layer=0; base=WB1;  nkt=2; Ksrc=51; ldm=64; coloff=0; }
    else if (p < 4096)  { layer=1; base=WB2;  nkt=2; Ksrc=64; ldm=64; coloff=0; p-=2048; }
    else if (p < 6144)  { layer=2; base=WB3;  nkt=2; Ksrc=64; ldm=64; coloff=0; p-=4096; }
    else if (p < 8192)  { layer=3; base=WB4;  nkt=2; Ksrc=64; ldm=65; coloff=1; p-=6144; }
    else if (p < 11264) { layer=4; base=WBR1; nkt=3; Ksrc=80; ldm=64; coloff=0; p-=8192; }
    else                { layer=5; base=WBR2; nkt=2; Ksrc=64; ldm=64; coloff=0; p-=11264; }
    const float* W = a.W[layer];
    int j = p & 3, lane = (p >> 2) & 63, fk = p >> 8;
    int q = lane >> 4, r = lane & 15;
    int kt = fk % nkt, it = fk / nkt;
    int m  = it * 16 + r;
    int k0 = kt * 32 + q * 8 + 2 * j;
    float w0 = (k0     < Ksrc) ? W[(size_t)k0 * ldm + m + coloff] : 0.0f;
    float w1 = (k0 + 1 < Ksrc) ? W[(size_t)(k0 + 1) * ldm + m + coloff] : 0.0f;
    u16 h0, l0, h1, l1; hsplit(w0, h0, l0); hsplit(w1, h1, l1);
    int half = nkt * 4 * 64 * 4;
    int idx  = base + (fk * 64 + lane) * 4 + j;
    a.ws[idx]        = (u32)h0 | ((u32)h1 << 16);   // element 2j (low half) = lower k
    a.ws[idx + half] = (u32)l0 | ((u32)l1 << 16);
}

// ================= MFMA layer: D[outfeat][point] = W * X, hi/lo fp16 split =================
template <int NKT, bool SHT>
__device__ __forceinline__ void mfma_layer(const u32* __restrict__ wb,
                                           const u32* act, int lane, f32x4 acc[4][4]) {
    const int q = lane >> 4, r = lane & 15;
    const int half = NKT * 4 * 64 * 4;
    #pragma unroll
    for (int jt = 0; jt < 4; jt++)
        #pragma unroll
        for (int it = 0; it < 4; it++)
            acc[jt][it] = (f32x4){0.f, 0.f, 0.f, 0.f};
    #pragma unroll
    for (int kt = 0; kt < NKT; kt++) {
        f16x8 whi[4], wlo[4];
        #pragma unroll
        for (int it = 0; it < 4; it++) {
            const u32* pb = wb + ((size_t)((it * NKT + kt) * 64 + lane)) * 4;
            u32x4 h = *(const u32x4*)pb;
            u32x4 l = *(const u32x4*)(pb + half);
            whi[it] = cast8h(h.x, h.y, h.z, h.w);
            wlo[it] = cast8h(l.x, l.y, l.z, l.w);
        }
        #pragma unroll
        for (int jt = 0; jt < 4; jt++) {
            bool zero = SHT && (kt == NKT - 1) && (q >= 2);
            const u32* rowp = act + (jt * 16 + r) * STR + kt * 32 + q * 8;
            u32 v[8];
            #pragma unroll
            for (int e = 0; e < 8; e++) v[e] = zero ? 0u : rowp[e];
            u32 xh[4], xl[4];
            #pragma unroll
            for (int j2 = 0; j2 < 4; j2++) {
                xh[j2] = (v[2*j2] >> 16) | (v[2*j2+1] & 0xffff0000u);
                xl[j2] = (v[2*j2] & 0xffffu) | (v[2*j2+1] << 16);
            }
            f16x8 bh = cast8h(xh[0], xh[1], xh[2], xh[3]);
            f16x8 bl = cast8h(xl[0], xl[1], xl[2], xl[3]);
            #pragma unroll
            for (int it = 0; it < 4; it++) {
                acc[jt][it] = __builtin_amdgcn_mfma_f32_16x16x32_f16(whi[it], bh, acc[jt][it], 0, 0, 0);
                acc[jt][it] = __builtin_amdgcn_mfma_f32_16x16x32_f16(whi[it], bl, acc[jt][it], 0, 0, 0);
                acc[jt][it] = __builtin_amdgcn_mfma_f32_16x16x32_f16(wlo[it], bh, acc[jt][it], 0, 0, 0);
            }
        }
    }
}

__device__ __forceinline__ void epilogue_gelu(f32x4 acc[4][4], const float* __restrict__ bias,
                                              u32* act, int lane) {
    const int q = lane >> 4, r = lane & 15;
    #pragma unroll
    for (int it = 0; it < 4; it++) {
        int mb = it * 16 + q * 4;
        float c0 = bias[mb], c1 = bias[mb + 1], c2 = bias[mb + 2], c3 = bias[mb + 3];
        #pragma unroll
        for (int jt = 0; jt < 4; jt++) {
            f32x4 d = acc[jt][it];
            u32* dst = act + (jt * 16 + r) * STR + mb;
            dst[0] = packhl(gelu_f(d[0] + c0));
            dst[1] = packhl(gelu_f(d[1] + c1));
            dst[2] = packhl(gelu_f(d[2] + c2));
            dst[3] = packhl(gelu_f(d[3] + c3));
        }
    }
}

// ================= fused main kernel: 1 wave/block, 64 points/wave =================
__global__ void __launch_bounds__(64) nerf_mfma(
    const float* __restrict__ pos, const float* __restrict__ dirs,
    const int* __restrict__ iter, const float* __restrict__ tables,
    const int* __restrict__ shifts,
    const float* __restrict__ b1, const float* __restrict__ b2,
    const float* __restrict__ b3,
    const float* __restrict__ W4, const float* __restrict__ b4,
    const float* __restrict__ rb1, const float* __restrict__ rb2,
    const float* __restrict__ R3, const float* __restrict__ rb3,
    const u32* __restrict__ wsb, float* __restrict__ out, int n)
{
    __shared__ u32 act[64 * STR];
    const int lane = threadIdx.x;
    const int i = blockIdx.x * 64 + lane;
    const bool valid = (i < n);
    u32* myrow = act + lane * STR;

    float px = 0.f, py = 0.f, pz = 0.f;
    if (valid) { px = pos[3*i]; py = pos[3*i+1]; pz = pos[3*i+2]; }

    // window
    double itd = (double)iter[0] / 10000.0;
    itd = itd < 0.0 ? 0.0 : (itd > 1.0 ? 1.0 : itd);
    float tL = (float)((0.3 + 0.7 * itd) * 24.0);

    // ---- encode -> LDS rows (feats 0..47, pos 48..50, zeros 51..63)
    #pragma unroll
    for (int k = 51; k < 64; k++) myrow[k] = 0u;
    myrow[48] = packhl(px); myrow[49] = packhl(py); myrow[50] = packhl(pz);
    #pragma unroll 2
    for (int l = 0; l < LVLS; l++) {
        float sc = powf(10.0f, (float)l * (-4.0f / 23.0f));
        float arg = fminf(fmaxf(tL - (float)l, 0.0f), 1.0f);
        float wl = 0.5f - 0.5f * cosf(3.14159265358979323846f * arg);
        int sx = shifts[3*l], sy = shifts[3*l+1], sz = shifts[3*l+2];
        float cx = px / sc, cy = py / sc, cz = pz / sc;
        float fx = floorf(cx), fy = floorf(cy), fz = floorf(cz);
        float rx = cx - fx, ry = cy - fy, rz = cz - fz;
        int bx = (int)fx + sx, by = (int)fy + sy, bz = (int)fz + sz;
        u32 hx0 = (u32)bx, hx1 = (u32)(bx + 1);
        u32 hy0 = (u32)by * 2654435761u, hy1 = (u32)(by + 1) * 2654435761u;
        u32 hz0 = (u32)bz * 805459861u,  hz1 = (u32)(bz + 1) * 805459861u;
        const float* tl = tables + 2 * ((size_t)l * CAPN);
        float a0 = 0.f, a1 = 0.f;
        #pragma unroll
        for (int c = 0; c < 8; c++) {
            u32 hx = (c & 1) ? hx1 : hx0;
            u32 hy = (c & 2) ? hy1 : hy0;
            u32 hz = (c & 4) ? hz1 : hz0;
            u32 idx = (hx ^ hy ^ hz) & (CAPN - 1);
            float w = ((c & 1) ? rx : 1.0f - rx);
            w *= ((c & 2) ? ry : 1.0f - ry);
            w *= ((c & 4) ? rz : 1.0f - rz);
            const float* tf = tl + 2 * (size_t)idx;
            a0 = fmaf(w, tf[0], a0);
            a1 = fmaf(w, tf[1], a1);
        }
        myrow[2*l]     = packhl(a0 * wl);
        myrow[2*l + 1] = packhl(a1 * wl);
    }
    __syncthreads();

    f32x4 acc[4][4];
    // ---- L1..L3
    mfma_layer<2, false>(wsb + WB1, act, lane, acc);
    epilogue_gelu(acc, b1, act, lane);
    __syncthreads();
    mfma_layer<2, false>(wsb + WB2, act, lane, acc);
    epilogue_gelu(acc, b2, act, lane);
    __syncthreads();
    mfma_layer<2, false>(wsb + WB3, act, lane, acc);
    epilogue_gelu(acc, b3, act, lane);
    __syncthreads();

    // ---- density (scalar, reads X3 rows) ----
    {
        float s = b4[0];
        #pragma unroll 8
        for (int k = 0; k < 64; k++) {
            float xv = unpackhl(myrow[k]);
            s = fmaf(xv, W4[(size_t)k * 65], s);
        }
        if (valid) out[(size_t)3 * n + i] = fmaxf(s, 0.f) + log1pf(expf(-fabsf(s)));
    }
    // ---- L4 (cols 1..64) ----
    mfma_layer<2, false>(wsb + WB4, act, lane, acc);
    epilogue_gelu(acc, b4 + 1, act, lane);   // gelu(feat_rgb) -> feats 0..63

    // ---- SH -> feats 64..79 ----
    {
        float dx = 0.f, dy = 0.f, dz = 0.f;
        if (valid) { dx = dirs[3*i]; dy = dirs[3*i+1]; dz = dirs[3*i+2]; }
        float xx = dx*dx, yy = dy*dy, zz = dz*dz;
        float sh[16];
        sh[0]  = 0.28209479177387814f;
        sh[1]  = -0.48860251190291987f * dy;
        sh[2]  = 0.48860251190291987f * dz;
        sh[3]  = -0.48860251190291987f * dx;
        sh[4]  = 1.0925484305920792f * dx * dy;
        sh[5]  = -1.0925484305920792f * dy * dz;
        sh[6]  = 0.94617469575756f * zz - 0.31539156525252f;
        sh[7]  = -1.0925484305920792f * dx * dz;
        sh[8]  = 0.5462742152960396f * (xx - yy);
        sh[9]  = -0.5900435899266435f * dy * (3.0f * xx - yy);
        sh[10] = 2.890611442640554f * dx * dy * dz;
        sh[11] = -0.4570457994644657f * dy * (4.0f * zz - xx - yy);
        sh[12] = 0.37317633259011546f * dz * (2.0f * zz - 3.0f * xx - 3.0f * yy);
        sh[13] = -0.4570457994644657f * dx * (4.0f * zz - xx - yy);
        sh[14] = 1.445305721320277f * dz * (xx - yy);
        sh[15] = -0.5900435899266435f * dx * (xx - 3.0f * yy);
        #pragma unroll
        for (int j = 0; j < 16; j++) myrow[64 + j] = packhl(sh[j]);
    }
    __syncthreads();

    // ---- R1 (K=80 via NKT=3 with zero tail), R2 ----
    mfma_layer<3, true>(wsb + WBR1, act, lane, acc);
    epilogue_gelu(acc, rb1, act, lane);
    __syncthreads();
    mfma_layer<2, false>(wsb + WBR2, act, lane, acc);
    epilogue_gelu(acc, rb2, act, lane);
    __syncthreads();

    // ---- R3 (scalar) + sigmoid ----
    {
        float y0 = rb3[0], y1 = rb3[1], y2 = rb3[2];
        #pragma unroll 8
        for (int k = 0; k < 64; k++) {
            float xv = unpackhl(myrow[k]);
            y0 = fmaf(xv, R3[(size_t)k * 3 + 0], y0);
            y1 = fmaf(xv, R3[(size_t)k * 3 + 1], y1);
            y2 = fmaf(xv, R3[(size_t)k * 3 + 2], y2);
        }
        if (valid) {
            out[(size_t)3 * i + 0] = sigmoid_f(y0);
            out[(size_t)3 * i + 1] = sigmoid_f(y1);
            out[(size_t)3 * i + 2] = sigmoid_f(y2);
        }
    }
}

extern "C" void kernel_launch(void* const* d_in, const int* in_sizes, int n_in,
                              void* d_out, int out_size, void* d_ws, size_t ws_size,
                              hipStream_t stream) {
    int n = in_sizes[0] / 3;

    PrepA pa;
    pa.W[0] = (const float*)d_in[5];   // W1 (51x64)
    pa.W[1] = (const float*)d_in[7];   // W2
    pa.W[2] = (const float*)d_in[9];   // W3
    pa.W[3] = (const float*)d_in[11];  // W4 (64x65), cols 1..64
    pa.W[4] = (const float*)d_in[13];  // R1 (80x64)
    pa.W[5] = (const float*)d_in[15];  // R2
    pa.ws = (u32*)d_ws;
    prep_weights<<<52, 256, 0, stream>>>(pa);

    int grid = (n + 63) / 64;
    nerf_mfma<<<grid, 64, 0, stream>>>(
        (const float*)d_in[0], (const float*)d_in[1], (const int*)d_in[2],
        (const float*)d_in[3], (const int*)d_in[4],
        (const float*)d_in[6],   // b1
        (const float*)d_in[8],   // b2
        (const float*)d_in[10],  // b3
        (const float*)d_in[11],  // W4 (density col)
        (const float*)d_in[12],  // b4
        (const float*)d_in[14],  // rb1
        (const float*)d_in[16],  // rb2
        (const float*)d_in[17],  // R3
        (const float*)d_in[18],  // rb3
        (const u32*)d_ws, (float*)d_out, n);
}

// Round 8
// 993.101 us; speedup vs baseline: 2.3129x; 1.7322x over previous
//
#include <hip/hip_runtime.h>
#include <math.h>

typedef unsigned short u16;
typedef unsigned int   u32;

#define LVLS 24
#define CAPN (1 << 18)
#define STR  81           // LDS act row stride in u32 (odd => benign bank pattern)

typedef float    f32x4 __attribute__((ext_vector_type(4)));
typedef _Float16 f16x8 __attribute__((ext_vector_type(8)));
typedef u32      u32x4 __attribute__((ext_vector_type(4)));

#if __has_builtin(__builtin_amdgcn_rcpf)
#define RCPF(x) __builtin_amdgcn_rcpf(x)
#else
#define RCPF(x) (1.0f / (x))
#endif
#if __has_builtin(__builtin_amdgcn_exp2f)
#define EXP2F(x) __builtin_amdgcn_exp2f(x)
#else
#define EXP2F(x) exp2f(x)
#endif

// ---- d_ws layout (u32 units): weight blobs then pf feature buffer
#define WB1   0
#define WB2   4096
#define WB3   8192
#define WB4   12288   /* W4 cols 1..64 */
#define WBR1  16384   /* NKT=3 */
#define WBR2  22528
#define PFOFF 32768   /* pf: LVLS * n u32, layout [level][point] */

__device__ __forceinline__ float h2f(u16 b) {
    union { u16 u; _Float16 h; } v; v.u = b; return (float)v.h;
}
__device__ __forceinline__ u16 f2h(float x) {
    union { _Float16 h; u16 u; } v; v.h = (_Float16)x; return v.u;   // RNE v_cvt_f16_f32
}
__device__ __forceinline__ void hsplit(float x, u16& h, u16& l) {
    h = f2h(x);
    float r = x - h2f(h);
    l = f2h(r);
}
__device__ __forceinline__ u32 packhl(float x) {
    u16 h, l; hsplit(x, h, l);
    return ((u32)h << 16) | l;
}
__device__ __forceinline__ float unpackhl(u32 w) {
    return h2f((u16)(w >> 16)) + h2f((u16)(w & 0xffffu));
}
// A&S 7.1.26 erf (|eps|<=1.5e-7), hw rcp + exp2
__device__ __forceinline__ float gelu_f(float x) {
    float z  = fabsf(x) * 0.70710678118654752f;
    float t  = RCPF(fmaf(0.3275911f, z, 1.0f));
    float e  = EXP2F(-z * z * 1.44269504088896340f);
    float p  = fmaf(1.061405429f, t, -1.453152027f);
    p = fmaf(p, t, 1.421413741f);
    p = fmaf(p, t, -0.284496736f);
    p = fmaf(p, t, 0.254829592f);
    p = p * t;
    float erfv = fmaf(-p, e, 1.0f);
    float se   = copysignf(erfv, x);
    return x * fmaf(0.5f, se, 0.5f);
}
__device__ __forceinline__ float sigmoid_f(float y) {
    return RCPF(1.0f + EXP2F(-y * 1.44269504088896340f));
}
__device__ __forceinline__ f16x8 cast8h(u32 a, u32 b, u32 c, u32 d) {
    union { u32 u[4]; f16x8 h; } v; v.u[0]=a; v.u[1]=b; v.u[2]=c; v.u[3]=d; return v.h;
}
__device__ __forceinline__ void window_scale(int l, const int* iter, float& sc, float& wl) {
    sc = powf(10.0f, (float)l * (-4.0f / 23.0f));
    double itd = (double)iter[0] / 10000.0;
    itd = itd < 0.0 ? 0.0 : (itd > 1.0 ? 1.0 : itd);
    float tL = (float)((0.3 + 0.7 * itd) * 24.0);
    float arg = fminf(fmaxf(tL - (float)l, 0.0f), 1.0f);
    wl = 0.5f - 0.5f * cosf(3.14159265358979323846f * arg);
}
// 8-corner hash interp for one (point, level) -> f0, f1 (window applied)
__device__ __forceinline__ void hash_level(float px, float py, float pz, float sc, float wl,
                                           int sx, int sy, int sz,
                                           const float* __restrict__ tl,
                                           float& f0, float& f1) {
    float cx = px / sc, cy = py / sc, cz = pz / sc;
    float fx = floorf(cx), fy = floorf(cy), fz = floorf(cz);
    float rx = cx - fx, ry = cy - fy, rz = cz - fz;
    int bx = (int)fx + sx, by = (int)fy + sy, bz = (int)fz + sz;
    u32 hx0 = (u32)bx, hx1 = (u32)(bx + 1);
    u32 hy0 = (u32)by * 2654435761u, hy1 = (u32)(by + 1) * 2654435761u;
    u32 hz0 = (u32)bz * 805459861u,  hz1 = (u32)(bz + 1) * 805459861u;
    float a0 = 0.f, a1 = 0.f;
    #pragma unroll
    for (int c = 0; c < 8; c++) {
        u32 hx = (c & 1) ? hx1 : hx0;
        u32 hy = (c & 2) ? hy1 : hy0;
        u32 hz = (c & 4) ? hz1 : hz0;
        u32 idx = (hx ^ hy ^ hz) & (CAPN - 1);
        float w = ((c & 1) ? rx : 1.0f - rx);
        w *= ((c & 2) ? ry : 1.0f - ry);
        w *= ((c & 4) ? rz : 1.0f - rz);
        const float* tf = tl + 2 * (size_t)idx;
        a0 = fmaf(w, tf[0], a0);
        a1 = fmaf(w, tf[1], a1);
    }
    f0 = a0 * wl;
    f1 = a1 * wl;
}

// ================= K1: level-major encode, coalesced fp16 feature writes =================
__global__ void __launch_bounds__(256) encode_k(
    const float* __restrict__ pos, const int* __restrict__ iter,
    const float* __restrict__ tables, const int* __restrict__ shifts,
    u32* __restrict__ pf, int n, int chunks) {
    int l = blockIdx.x / chunks;
    int p = (blockIdx.x - l * chunks) * 256 + threadIdx.x;
    if (p >= n) return;
    float px = pos[3*p], py = pos[3*p+1], pz = pos[3*p+2];
    float sc, wl; window_scale(l, iter, sc, wl);
    float f0, f1;
    hash_level(px, py, pz, sc, wl, shifts[3*l], shifts[3*l+1], shifts[3*l+2],
               tables + 2 * ((size_t)l * CAPN), f0, f1);
    // x256 pre-scale (exact pow2; W1 feature rows carry 1/256) keeps fp16 normal
    u32 v = (u32)f2h(f0 * 256.0f) | ((u32)f2h(f1 * 256.0f) << 16);
    pf[(size_t)l * n + p] = v;
}

// ================= prep: split weights into frag-ordered hi/lo fp16 blobs =================
struct PrepA { const float* W[6]; u32* ws; };

__global__ void prep_weights(PrepA a) {
    int tid = blockIdx.x * 256 + threadIdx.x;
    if (tid >= 13312) return;
    int p = tid, base, nkt, Ksrc, ldm, coloff, layer;
    if      (p < 2048)  { layer=0; base=WB1;  nkt=2; Ksrc=51; ldm=64; coloff=0; }
    else if (p < 4096)  { layer=1; base=WB2;  nkt=2; Ksrc=64; ldm=64; coloff=0; p-=2048; }
    else if (p < 6144)  { layer=2; base=WB3;  nkt=2; Ksrc=64; ldm=64; coloff=0; p-=4096; }
    else if (p < 8192)  { layer=3; base=WB4;  nkt=2; Ksrc=64; ldm=65; coloff=1; p-=6144; }
    else if (p < 11264) { layer=4; base=WBR1; nkt=3; Ksrc=80; ldm=64; coloff=0; p-=8192; }
    else                { layer=5; base=WBR2; nkt=2; Ksrc=64; ldm=64; coloff=0; p-=11264; }
    const float* W = a.W[layer];
    int j = p & 3, lane = (p >> 2) & 63, fk = p >> 8;
    int q = lane >> 4, r = lane & 15;
    int kt = fk % nkt, it = fk / nkt;
    int m  = it * 16 + r;
    int k0 = kt * 32 + q * 8 + 2 * j;
    float w0 = (k0     < Ksrc) ? W[(size_t)k0 * ldm + m + coloff] : 0.0f;
    float w1 = (k0 + 1 < Ksrc) ? W[(size_t)(k0 + 1) * ldm + m + coloff] : 0.0f;
    if (layer == 0 && k0     < 48) w0 *= (1.0f / 256.0f);   // undo x256 feature pre-scale
    if (layer == 0 && k0 + 1 < 48) w1 *= (1.0f / 256.0f);
    u16 h0, l0, h1, l1; hsplit(w0, h0, l0); hsplit(w1, h1, l1);
    int half = nkt * 4 * 64 * 4;
    int idx  = base + (fk * 64 + lane) * 4 + j;
    a.ws[idx]        = (u32)h0 | ((u32)h1 << 16);
    a.ws[idx + half] = (u32)l0 | ((u32)l1 << 16);
}

// ================= MFMA layer: D[outfeat][point] = W * X, hi/lo fp16 split =================
template <int NKT, bool SHT>
__device__ __forceinline__ void mfma_layer(const u32* __restrict__ wb,
                                           const u32* act, int lane, f32x4 acc[4][4]) {
    const int q = lane >> 4, r = lane & 15;
    const int half = NKT * 4 * 64 * 4;
    #pragma unroll
    for (int jt = 0; jt < 4; jt++)
        #pragma unroll
        for (int it = 0; it < 4; it++)
            acc[jt][it] = (f32x4){0.f, 0.f, 0.f, 0.f};
    #pragma unroll
    for (int kt = 0; kt < NKT; kt++) {
        f16x8 whi[4], wlo[4];
        #pragma unroll
        for (int it = 0; it < 4; it++) {
            const u32* pb = wb + ((size_t)((it * NKT + kt) * 64 + lane)) * 4;
            u32x4 h = *(const u32x4*)pb;
            u32x4 l = *(const u32x4*)(pb + half);
            whi[it] = cast8h(h.x, h.y, h.z, h.w);
            wlo[it] = cast8h(l.x, l.y, l.z, l.w);
        }
        #pragma unroll
        for (int jt = 0; jt < 4; jt++) {
            bool zero = SHT && (kt == NKT - 1) && (q >= 2);
            const u32* rowp = act + (jt * 16 + r) * STR + kt * 32 + q * 8;
            u32 v[8];
            #pragma unroll
            for (int e = 0; e < 8; e++) v[e] = zero ? 0u : rowp[e];
            u32 xh[4], xl[4];
            #pragma unroll
            for (int j2 = 0; j2 < 4; j2++) {
                xh[j2] = (v[2*j2] >> 16) | (v[2*j2+1] & 0xffff0000u);
                xl[j2] = (v[2*j2] & 0xffffu) | (v[2*j2+1] << 16);
            }
            f16x8 bh = cast8h(xh[0], xh[1], xh[2], xh[3]);
            f16x8 bl = cast8h(xl[0], xl[1], xl[2], xl[3]);
            #pragma unroll
            for (int it = 0; it < 4; it++) {
                acc[jt][it] = __builtin_amdgcn_mfma_f32_16x16x32_f16(whi[it], bh, acc[jt][it], 0, 0, 0);
                acc[jt][it] = __builtin_amdgcn_mfma_f32_16x16x32_f16(whi[it], bl, acc[jt][it], 0, 0, 0);
                acc[jt][it] = __builtin_amdgcn_mfma_f32_16x16x32_f16(wlo[it], bh, acc[jt][it], 0, 0, 0);
            }
        }
    }
}

__device__ __forceinline__ void epilogue_gelu(f32x4 acc[4][4], const float* __restrict__ bias,
                                              u32* act, int lane) {
    const int q = lane >> 4, r = lane & 15;
    #pragma unroll
    for (int it = 0; it < 4; it++) {
        int mb = it * 16 + q * 4;
        float c0 = bias[mb], c1 = bias[mb + 1], c2 = bias[mb + 2], c3 = bias[mb + 3];
        #pragma unroll
        for (int jt = 0; jt < 4; jt++) {
            f32x4 d = acc[jt][it];
            u32* dst = act + (jt * 16 + r) * STR + mb;
            dst[0] = packhl(gelu_f(d[0] + c0));
            dst[1] = packhl(gelu_f(d[1] + c1));
            dst[2] = packhl(gelu_f(d[2] + c2));
            dst[3] = packhl(gelu_f(d[3] + c3));
        }
    }
}

// ================= K2: MFMA MLP chain; ENC=true inlines encode (ws fallback) =================
template <bool ENC>
__global__ void __launch_bounds__(64) nerf_mfma(
    const float* __restrict__ pos, const float* __restrict__ dirs,
    const int* __restrict__ iter, const float* __restrict__ tables,
    const int* __restrict__ shifts,
    const float* __restrict__ b1, const float* __restrict__ b2,
    const float* __restrict__ b3,
    const float* __restrict__ W4, const float* __restrict__ b4,
    const float* __restrict__ rb1, const float* __restrict__ rb2,
    const float* __restrict__ R3, const float* __restrict__ rb3,
    const u32* __restrict__ wsb, const u32* __restrict__ pf,
    float* __restrict__ out, int n)
{
    __shared__ u32 act[64 * STR];
    const int lane = threadIdx.x;
    const int i = blockIdx.x * 64 + lane;
    const bool valid = (i < n);
    u32* myrow = act + lane * STR;

    float px = 0.f, py = 0.f, pz = 0.f;
    if (valid) { px = pos[3*i]; py = pos[3*i+1]; pz = pos[3*i+2]; }

    #pragma unroll
    for (int k = 51; k < 64; k++) myrow[k] = 0u;
    myrow[48] = packhl(px); myrow[49] = packhl(py); myrow[50] = packhl(pz);

    if (ENC) {
        #pragma unroll 2
        for (int l = 0; l < LVLS; l++) {
            float sc, wl; window_scale(l, iter, sc, wl);
            float f0, f1;
            hash_level(px, py, pz, sc, wl, shifts[3*l], shifts[3*l+1], shifts[3*l+2],
                       tables + 2 * ((size_t)l * CAPN), f0, f1);
            myrow[2*l]     = (u32)f2h(f0 * 256.0f) << 16;
            myrow[2*l + 1] = (u32)f2h(f1 * 256.0f) << 16;
        }
    } else {
        u32 v[LVLS];
        #pragma unroll
        for (int l = 0; l < LVLS; l++) v[l] = valid ? pf[(size_t)l * n + i] : 0u;
        #pragma unroll
        for (int l = 0; l < LVLS; l++) {
            myrow[2*l]     = v[l] << 16;           // f0 hi, lo=0
            myrow[2*l + 1] = v[l] & 0xffff0000u;   // f1 hi, lo=0
        }
    }
    __syncthreads();

    f32x4 acc[4][4];
    mfma_layer<2, false>(wsb + WB1, act, lane, acc);
    epilogue_gelu(acc, b1, act, lane);
    __syncthreads();
    mfma_layer<2, false>(wsb + WB2, act, lane, acc);
    epilogue_gelu(acc, b2, act, lane);
    __syncthreads();
    mfma_layer<2, false>(wsb + WB3, act, lane, acc);
    epilogue_gelu(acc, b3, act, lane);
    __syncthreads();

    // density (scalar dot over X3)
    {
        float s = b4[0];
        #pragma unroll 8
        for (int k = 0; k < 64; k++) {
            float xv = unpackhl(myrow[k]);
            s = fmaf(xv, W4[(size_t)k * 65], s);
        }
        if (valid) out[(size_t)3 * n + i] = fmaxf(s, 0.f) + log1pf(expf(-fabsf(s)));
    }
    mfma_layer<2, false>(wsb + WB4, act, lane, acc);
    epilogue_gelu(acc, b4 + 1, act, lane);

    // SH -> feats 64..79
    {
        float dx = 0.f, dy = 0.f, dz = 0.f;
        if (valid) { dx = dirs[3*i]; dy = dirs[3*i+1]; dz = dirs[3*i+2]; }
        float xx = dx*dx, yy = dy*dy, zz = dz*dz;
        float sh[16];
        sh[0]  = 0.28209479177387814f;
        sh[1]  = -0.48860251190291987f * dy;
        sh[2]  = 0.48860251190291987f * dz;
        sh[3]  = -0.48860251190291987f * dx;
        sh[4]  = 1.0925484305920792f * dx * dy;
        sh[5]  = -1.0925484305920792f * dy * dz;
        sh[6]  = 0.94617469575756f * zz - 0.31539156525252f;
        sh[7]  = -1.0925484305920792f * dx * dz;
        sh[8]  = 0.5462742152960396f * (xx - yy);
        sh[9]  = -0.5900435899266435f * dy * (3.0f * xx - yy);
        sh[10] = 2.890611442640554f * dx * dy * dz;
        sh[11] = -0.4570457994644657f * dy * (4.0f * zz - xx - yy);
        sh[12] = 0.37317633259011546f * dz * (2.0f * zz - 3.0f * xx - 3.0f * yy);
        sh[13] = -0.4570457994644657f * dx * (4.0f * zz - xx - yy);
        sh[14] = 1.445305721320277f * dz * (xx - yy);
        sh[15] = -0.5900435899266435f * dx * (xx - 3.0f * yy);
        #pragma unroll
        for (int j = 0; j < 16; j++) myrow[64 + j] = packhl(sh[j]);
    }
    __syncthreads();

    mfma_layer<3, true>(wsb + WBR1, act, lane, acc);
    epilogue_gelu(acc, rb1, act, lane);
    __syncthreads();
    mfma_layer<2, false>(wsb + WBR2, act, lane, acc);
    epilogue_gelu(acc, rb2, act, lane);
    __syncthreads();

    // R3 (scalar) + sigmoid
    {
        float y0 = rb3[0], y1 = rb3[1], y2 = rb3[2];
        #pragma unroll 8
        for (int k = 0; k < 64; k++) {
            float xv = unpackhl(myrow[k]);
            y0 = fmaf(xv, R3[(size_t)k * 3 + 0], y0);
            y1 = fmaf(xv, R3[(size_t)k * 3 + 1], y1);
            y2 = fmaf(xv, R3[(size_t)k * 3 + 2], y2);
        }
        if (valid) {
            out[(size_t)3 * i + 0] = sigmoid_f(y0);
            out[(size_t)3 * i + 1] = sigmoid_f(y1);
            out[(size_t)3 * i + 2] = sigmoid_f(y2);
        }
    }
}

extern "C" void kernel_launch(void* const* d_in, const int* in_sizes, int n_in,
                              void* d_out, int out_size, void* d_ws, size_t ws_size,
                              hipStream_t stream) {
    int n = in_sizes[0] / 3;

    PrepA pa;
    pa.W[0] = (const float*)d_in[5];   // W1 (51x64)
    pa.W[1] = (const float*)d_in[7];   // W2
    pa.W[2] = (const float*)d_in[9];   // W3
    pa.W[3] = (const float*)d_in[11];  // W4 (64x65), cols 1..64
    pa.W[4] = (const float*)d_in[13];  // R1 (80x64)
    pa.W[5] = (const float*)d_in[15];  // R2
    pa.ws = (u32*)d_ws;
    prep_weights<<<52, 256, 0, stream>>>(pa);

    size_t need = ((size_t)PFOFF + (size_t)LVLS * (size_t)n) * 4;
    bool split = (ws_size >= need);
    u32* pf = (u32*)d_ws + PFOFF;
    int grid = (n + 63) / 64;

    if (split) {
        int chunks = (n + 255) / 256;
        encode_k<<<LVLS * chunks, 256, 0, stream>>>(
            (const float*)d_in[0], (const int*)d_in[2],
            (const float*)d_in[3], (const int*)d_in[4], pf, n, chunks);
        nerf_mfma<false><<<grid, 64, 0, stream>>>(
            (const float*)d_in[0], (const float*)d_in[1], (const int*)d_in[2],
            (const float*)d_in[3], (const int*)d_in[4],
            (const float*)d_in[6], (const float*)d_in[8], (const float*)d_in[10],
            (const float*)d_in[11], (const float*)d_in[12],
            (const float*)d_in[14], (const float*)d_in[16],
            (const float*)d_in[17], (const float*)d_in[18],
            (const u32*)d_ws, pf, (float*)d_out, n);
    } else {
        nerf_mfma<true><<<grid, 64, 0, stream>>>(
            (const float*)d_in[0], (const float*)d_in[1], (const int*)d_in[2],
            (const float*)d_in[3], (const int*)d_in[4],
            (const float*)d_in[6], (const float*)d_in[8], (const float*)d_in[10],
            (const float*)d_in[11], (const float*)d_in[12],
            (const float*)d_in[14], (const float*)d_in[16],
            (const float*)d_in[17], (const float*)d_in[18],
            (const u32*)d_ws, pf, (float*)d_out, n);
    }
}